// Round 10
// baseline (481.628 us; speedup 1.0000x reference)
//
#include <hip/hip_runtime.h>

#define TT 8192
#define CIN 512
#define COUT 512
#define NB 8
#define KTOT 1536   // 3 * CIN
#define NT 24       // K tiles of 64

typedef __attribute__((ext_vector_type(4))) float f32x4;
typedef __attribute__((ext_vector_type(8))) short bf16x8;
typedef __attribute__((ext_vector_type(8))) unsigned short u16x8;

#define GLD16(g, l) __builtin_amdgcn_global_load_lds(                      \
    (const __attribute__((address_space(1))) void*)(g),                    \
    (__attribute__((address_space(3))) void*)(l), 16, 0, 0)

#define CFENCE() asm volatile("" ::: "memory")
#define SBAR() do { CFENCE(); __builtin_amdgcn_s_barrier(); CFENCE(); } while (0)
#define VMCNT16() asm volatile("s_waitcnt vmcnt(16)" ::: "memory")
#define VMCNT8() asm volatile("s_waitcnt vmcnt(8)" ::: "memory")
#define VMCNT0() asm volatile("s_waitcnt vmcnt(0)" ::: "memory")
#define LGKM0() asm volatile("s_waitcnt lgkmcnt(0)" ::: "memory")
#define MFMA(a_, b_, c_) __builtin_amdgcn_mfma_f32_16x16x32_bf16((a_), (b_), (c_), 0, 0, 0)

__device__ inline unsigned short f2bf(float f) {
  union { float f; unsigned int u; } v; v.f = f;
  unsigned int u = v.u;
  unsigned int r = (u + 0x7FFFu + ((u >> 16) & 1u)) >> 16;  // RNE
  return (unsigned short)r;
}

__global__ void k_convert_w(const float* __restrict__ W0, const float* __restrict__ W1,
                            const float* __restrict__ W2, unsigned short* __restrict__ Wb) {
  int i = blockIdx.x * 256 + threadIdx.x;
  if (i >= COUT * CIN) return;
  const float* Ws = blockIdx.y == 0 ? W0 : (blockIdx.y == 1 ? W1 : W2);
  int o = i >> 9, c = i & 511;
  Wb[(size_t)o * KTOT + blockIdx.y * CIN + c] = f2bf(Ws[i]);
}

// x (B, C, T) fp32 -> xbT (T, C) bf16 per batch. grid (T/64, C/64, nb), block 256
__global__ void k_transpose(const float* __restrict__ x, unsigned short* __restrict__ xbT,
                            int b_base) {
  int b = b_base + blockIdx.z;
  const float* xb = x + (size_t)b * CIN * TT;
  unsigned short* xo = xbT + (size_t)blockIdx.z * TT * CIN;
  __shared__ float tile[64][65];
  int t0 = blockIdx.x * 64, c0 = blockIdx.y * 64;
  int tid = threadIdx.x;
#pragma unroll
  for (int it = 0; it < 16; ++it) {
    int L = it * 256 + tid;
    int c = L >> 6, t = L & 63;
    tile[c][t] = xb[(size_t)(c0 + c) * TT + (t0 + t)];
  }
  __syncthreads();
#pragma unroll
  for (int it = 0; it < 16; ++it) {
    int L = it * 256 + tid;
    int t = L >> 6, c = L & 63;
    xo[(size_t)(t0 + t) * CIN + (c0 + c)] = f2bf(tile[c][t]);
  }
}

// ---------------- FAST: 256x256, 4 waves x (128x128), dil==1 only ----------------
// grid (8, 64), block 256. Early-exits (whole block) if any d >= 2 in its t-range.
// LDS read amp: 4 waves x (128+128)x64x2B = 128 KB/tile (vs 192 KB at 8 waves).
__global__ __launch_bounds__(256) void k_gemm_w4(
    const unsigned short* __restrict__ Wb, const unsigned short* __restrict__ xbT,
    const float* __restrict__ d, const float* __restrict__ bias,
    float* __restrict__ out) {
  const int b = blockIdx.x;                    // batch = id%8 -> XCD
  const int t0 = (blockIdx.y >> 1) * 256;      // t-tile
  const int row0 = (blockIdx.y & 1) * 256;     // M-tile
  const int tid = threadIdx.x;
  // fast-path predicate: all dil == 1  <=>  all d < 2
  {
    float dv = d[(size_t)b * TT + t0 + tid];
    if (__syncthreads_or(dv >= 2.0f)) return;  // slow kernel handles this block
  }
  __shared__ __align__(16) unsigned short As[2][256 * 64];
  __shared__ __align__(16) unsigned short Bs[2][256 * 64];
  const unsigned short* xb = xbT + (size_t)b * TT * CIN;
  const int lane = tid & 63, wid = tid >> 6;
  const int wr = wid >> 1, wc = wid & 1;
  const int l15 = lane & 15, kg = lane >> 4;

  // staging: round j (0..7) covers rows j*32 + (tid>>3), chunk slot tid&7
  const int srow = tid >> 3;
  const int cSrc8 = (((tid & 7) ^ ((tid >> 4) & 7))) * 8;  // swizzled 16B chunk
  int aOff[8], bOffC[8];
#pragma unroll
  for (int j = 0; j < 8; ++j) {
    int r = j * 32 + srow;
    aOff[j] = (row0 + r) * KTOT + cSrc8;
    bOffC[j] = (t0 + r) * CIN + cSrc8;
  }

  // fragment read offsets (swizzled): row r, chunk (kh*4+kg) ^ ((r>>1)&7)
  const int s7 = l15 >> 1;
  const int chunk0 = (kg ^ (s7 & 3)) + (s7 & 4);
  const int dK = (l15 & 8) ? -32 : 32;
  int aRd[8], bRd[8];
#pragma unroll
  for (int mi = 0; mi < 8; ++mi)
    aRd[mi] = (wr * 128 + mi * 16 + l15) * 64 + chunk0 * 8;
#pragma unroll
  for (int ni = 0; ni < 8; ++ni)
    bRd[ni] = (wc * 128 + ni * 16 + l15) * 64 + chunk0 * 8;

#define W4_STAGE_A(tc_, buf_) do {                                            \
    _Pragma("unroll") for (int j = 0; j < 8; ++j)                             \
      GLD16(Wb + aOff[j] + (tc_) * 64, &As[buf_][j * 2048 + wid * 512]);      \
  } while (0)
  // seg: 0 -> row-1 (edge t==0 -> +1), 1 -> row, 2 -> row+1 (edge t==TT-1 -> 0)
#define W4_STAGE_B(tc_, buf_) do {                                            \
    int seg_ = (tc_) >> 3; int k8_ = ((tc_) & 7) * 64;                        \
    _Pragma("unroll") for (int j = 0; j < 8; ++j) {                           \
      int tj_ = t0 + j * 32 + srow;                                           \
      int sh_ = (seg_ == 0) ? ((tj_ == 0) ? (int)CIN : -(int)CIN)             \
              : ((seg_ == 1) ? 0 : ((tj_ == TT - 1) ? 0 : (int)CIN));         \
      GLD16(xb + bOffC[j] + sh_ + k8_, &Bs[buf_][j * 2048 + wid * 512]);      \
    }                                                                         \
  } while (0)

  // prologue: tiles 0,1 staged; drain tile0's 16 (per-thread), keep tile1's
  W4_STAGE_A(0, 0); W4_STAGE_B(0, 0);
  W4_STAGE_A(1, 1); W4_STAGE_B(1, 1);
  VMCNT16();
  SBAR();

  bf16x8 af[8][2], bf[4][2];
  f32x4 acc[8][8] = {};

#pragma unroll 2
  for (int tc = 0; tc < NT; ++tc) {
    const int cur = tc & 1;
    // bf half0 first, then af: first MFMA can start while later reads drain
#pragma unroll
    for (int ni = 0; ni < 4; ++ni) {
      bf[ni][0] = *(const bf16x8*)&Bs[cur][bRd[ni]];
      bf[ni][1] = *(const bf16x8*)&Bs[cur][bRd[ni] + dK];
    }
#pragma unroll
    for (int mi = 0; mi < 8; ++mi) {
      af[mi][0] = *(const bf16x8*)&As[cur][aRd[mi]];
      af[mi][1] = *(const bf16x8*)&As[cur][aRd[mi] + dK];
    }
    __builtin_amdgcn_s_setprio(1);
#pragma unroll
    for (int mi = 0; mi < 8; ++mi)
#pragma unroll
      for (int ni = 0; ni < 4; ++ni) {
        acc[mi][ni] = MFMA(af[mi][0], bf[ni][0], acc[mi][ni]);
        acc[mi][ni] = MFMA(af[mi][1], bf[ni][1], acc[mi][ni]);
      }
    __builtin_amdgcn_s_setprio(0);
    // bf half1 (reuses regs); overlaps the MFMA block above via compiler lgkmcnt
#pragma unroll
    for (int ni = 0; ni < 4; ++ni) {
      bf[ni][0] = *(const bf16x8*)&Bs[cur][bRd[4 + ni]];
      bf[ni][1] = *(const bf16x8*)&Bs[cur][bRd[4 + ni] + dK];
    }
    __builtin_amdgcn_s_setprio(1);
#pragma unroll
    for (int mi = 0; mi < 8; ++mi)
#pragma unroll
      for (int ni = 0; ni < 4; ++ni) {
        acc[mi][4 + ni] = MFMA(af[mi][0], bf[ni][0], acc[mi][4 + ni]);
        acc[mi][4 + ni] = MFMA(af[mi][1], bf[ni][1], acc[mi][4 + ni]);
      }
    __builtin_amdgcn_s_setprio(0);
    LGKM0();   // all [cur] reads complete (own wave)
    SBAR();    // cross-wave: [cur] reusable
    if (tc + 2 < NT) { W4_STAGE_A(tc + 2, cur); W4_STAGE_B(tc + 2, cur); }
    if (tc + 2 < NT) { VMCNT16(); }       // drain (t+1) set; keep (t+2) in flight
    else if (tc + 1 < NT) { VMCNT0(); }
    SBAR();
  }

  // epilogue: bias + fp32 store
  float* ob = out + (size_t)b * COUT * TT;
#pragma unroll
  for (int mi = 0; mi < 8; ++mi) {
    int m0 = row0 + wr * 128 + mi * 16 + kg * 4;
#pragma unroll
    for (int ni = 0; ni < 8; ++ni) {
      int t = t0 + wc * 128 + ni * 16 + l15;
      f32x4 v = acc[mi][ni];
#pragma unroll
      for (int j = 0; j < 4; ++j)
        ob[(size_t)(m0 + j) * TT + t] = v[j] + bias[m0 + j];
    }
  }
}

// ---------------- SLOW (general d): r9 kernel + complementary early-exit ----------------
// grid (8, 64), block 512 (8 waves, 2M x 4N)
__global__ __launch_bounds__(512) void k_gemm256(
    const unsigned short* __restrict__ Wb, const unsigned short* __restrict__ xbT,
    const float* __restrict__ d, const float* __restrict__ bias,
    float* __restrict__ out) {
  const int b = blockIdx.x;
  const int t0 = (blockIdx.y >> 1) * 256;
  const int row0 = (blockIdx.y & 1) * 256;
  const int tid = threadIdx.x;
  {
    float dv = d[(size_t)b * TT + t0 + (tid & 255)];
    if (!__syncthreads_or(dv >= 2.0f)) return;  // fast kernel already did it
  }
  __shared__ __align__(16) unsigned short As[2][256 * 64];
  __shared__ __align__(16) unsigned short Bs[2][256 * 64];
  const unsigned short* xb = xbT + (size_t)b * TT * CIN;
  const int lane = tid & 63, wid = tid >> 6;
  const int wr = wid >> 2, wc = wid & 3;
  const int l15 = lane & 15, kg = lane >> 4;

  const int srow = tid >> 3;
  const int cSrc8 = (((tid & 7) ^ ((tid >> 4) & 7))) * 8;
  int aOff[4];
  int bOff[3][4];
#pragma unroll
  for (int j = 0; j < 4; ++j) {
    int r = j * 64 + srow;
    aOff[j] = (row0 + r) * KTOT + cSrc8;
    int t = t0 + r;
    float dv = d[(size_t)b * TT + t];
    int dil = (int)dv; if (dil < 1) dil = 1;
    int p = t - dil; if (p < 0) p = -p; p &= (TT - 1);
    int f0 = t + dil;
    int f = (f0 >= TT) ? (TT - 1 - (f0 & (TT - 1))) : f0;
    bOff[0][j] = p * CIN + cSrc8;
    bOff[1][j] = t * CIN + cSrc8;
    bOff[2][j] = f * CIN + cSrc8;
  }

  const int s7 = l15 >> 1;
  const int chunk0 = (kg ^ (s7 & 3)) + (s7 & 4);
  const int dK = (l15 & 8) ? -32 : 32;
  int aRd[2][4], bRd[2][2];
#pragma unroll
  for (int mh = 0; mh < 2; ++mh)
#pragma unroll
    for (int mi = 0; mi < 4; ++mi)
      aRd[mh][mi] = (wr * 128 + mh * 64 + mi * 16 + l15) * 64 + chunk0 * 8;
#pragma unroll
  for (int nh = 0; nh < 2; ++nh)
#pragma unroll
    for (int ni = 0; ni < 2; ++ni)
      bRd[nh][ni] = (wc * 64 + nh * 32 + ni * 16 + l15) * 64 + chunk0 * 8;

#define STAGE_A2(tc_, buf_, jp_) do {                                         \
    _Pragma("unroll") for (int j = 2 * (jp_); j < 2 * (jp_) + 2; ++j)         \
      GLD16(Wb + aOff[j] + (tc_) * 64, &As[buf_][j * 4096 + wid * 512]);      \
  } while (0)
#define STAGE_B2(tc_, buf_, jp_) do {                                         \
    _Pragma("unroll") for (int j = 2 * (jp_); j < 2 * (jp_) + 2; ++j)         \
      GLD16(xb + bOff[(tc_) >> 3][j] + ((tc_) & 7) * 64,                      \
            &Bs[buf_][j * 4096 + wid * 512]);                                 \
  } while (0)

  STAGE_A2(0, 0, 0); STAGE_A2(0, 0, 1);
  STAGE_B2(0, 0, 0); STAGE_B2(0, 0, 1);
  STAGE_A2(1, 1, 0); STAGE_A2(1, 1, 1);
  STAGE_B2(1, 1, 0); STAGE_B2(1, 1, 1);
  VMCNT8();
  SBAR();

  bf16x8 af0[4][2], af1[4][2], bfr[2][2];
  f32x4 acc[8][4] = {};

#pragma unroll
  for (int mi = 0; mi < 4; ++mi) {
    af0[mi][0] = *(const bf16x8*)&As[0][aRd[0][mi]];
    af0[mi][1] = *(const bf16x8*)&As[0][aRd[0][mi] + dK];
  }
#pragma unroll
  for (int ni = 0; ni < 2; ++ni) {
    bfr[ni][0] = *(const bf16x8*)&Bs[0][bRd[0][ni]];
    bfr[ni][1] = *(const bf16x8*)&Bs[0][bRd[0][ni] + dK];
  }

#pragma unroll 2
  for (int tc = 0; tc < NT; ++tc) {
    const int cur = tc & 1;
#pragma unroll
    for (int mi = 0; mi < 4; ++mi) {
      af1[mi][0] = *(const bf16x8*)&As[cur][aRd[1][mi]];
      af1[mi][1] = *(const bf16x8*)&As[cur][aRd[1][mi] + dK];
    }
    __builtin_amdgcn_s_setprio(1);
#pragma unroll
    for (int mi = 0; mi < 4; ++mi)
#pragma unroll
      for (int ni = 0; ni < 2; ++ni) {
        acc[mi][ni] = MFMA(af0[mi][0], bfr[ni][0], acc[mi][ni]);
        acc[mi][ni] = MFMA(af0[mi][1], bfr[ni][1], acc[mi][ni]);
      }
    __builtin_amdgcn_s_setprio(0);
    __builtin_amdgcn_s_setprio(1);
#pragma unroll
    for (int mi = 0; mi < 4; ++mi)
#pragma unroll
      for (int ni = 0; ni < 2; ++ni) {
        acc[4 + mi][ni] = MFMA(af1[mi][0], bfr[ni][0], acc[4 + mi][ni]);
        acc[4 + mi][ni] = MFMA(af1[mi][1], bfr[ni][1], acc[4 + mi][ni]);
      }
    __builtin_amdgcn_s_setprio(0);
#pragma unroll
    for (int ni = 0; ni < 2; ++ni) {
      bfr[ni][0] = *(const bf16x8*)&Bs[cur][bRd[1][ni]];
      bfr[ni][1] = *(const bf16x8*)&Bs[cur][bRd[1][ni] + dK];
    }
    LGKM0();
    SBAR();
    if (tc + 2 < NT) { STAGE_A2(tc + 2, cur, 0); STAGE_A2(tc + 2, cur, 1); }
    __builtin_amdgcn_s_setprio(1);
#pragma unroll
    for (int mi = 0; mi < 4; ++mi)
#pragma unroll
      for (int ni = 0; ni < 2; ++ni) {
        acc[mi][2 + ni] = MFMA(af0[mi][0], bfr[ni][0], acc[mi][2 + ni]);
        acc[mi][2 + ni] = MFMA(af0[mi][1], bfr[ni][1], acc[mi][2 + ni]);
      }
    __builtin_amdgcn_s_setprio(0);
    if (tc + 2 < NT) { STAGE_B2(tc + 2, cur, 0); STAGE_B2(tc + 2, cur, 1); }
    __builtin_amdgcn_s_setprio(1);
#pragma unroll
    for (int mi = 0; mi < 4; ++mi)
#pragma unroll
      for (int ni = 0; ni < 2; ++ni) {
        acc[4 + mi][2 + ni] = MFMA(af1[mi][0], bfr[ni][0], acc[4 + mi][2 + ni]);
        acc[4 + mi][2 + ni] = MFMA(af1[mi][1], bfr[ni][1], acc[4 + mi][2 + ni]);
      }
    __builtin_amdgcn_s_setprio(0);
    if (tc + 2 < NT) { VMCNT8(); }
    else if (tc + 1 < NT) { VMCNT0(); }
    SBAR();
    if (tc + 1 < NT) {
#pragma unroll
      for (int mi = 0; mi < 4; ++mi) {
        af0[mi][0] = *(const bf16x8*)&As[cur ^ 1][aRd[0][mi]];
        af0[mi][1] = *(const bf16x8*)&As[cur ^ 1][aRd[0][mi] + dK];
      }
#pragma unroll
      for (int ni = 0; ni < 2; ++ni) {
        bfr[ni][0] = *(const bf16x8*)&Bs[cur ^ 1][bRd[0][ni]];
        bfr[ni][1] = *(const bf16x8*)&Bs[cur ^ 1][bRd[0][ni] + dK];
      }
    }
  }

  float* ob = out + (size_t)b * COUT * TT;
#pragma unroll
  for (int mh = 0; mh < 2; ++mh)
#pragma unroll
    for (int mi = 0; mi < 4; ++mi) {
      int m0 = row0 + wr * 128 + mh * 64 + mi * 16 + kg * 4;
#pragma unroll
      for (int nh = 0; nh < 2; ++nh)
#pragma unroll
        for (int ni = 0; ni < 2; ++ni) {
          int t = t0 + wc * 64 + nh * 32 + ni * 16 + l15;
          f32x4 v = acc[mh * 4 + mi][nh * 2 + ni];
#pragma unroll
          for (int j = 0; j < 4; ++j)
            ob[(size_t)(m0 + j) * TT + t] = v[j] + bias[m0 + j];
        }
    }
}

// ---------------- fallback 128x128 (small ws) ----------------
__global__ __launch_bounds__(256) void k_gemm(
    const unsigned short* __restrict__ Wb, const unsigned short* __restrict__ xbT,
    const float* __restrict__ d, const float* __restrict__ bias,
    float* __restrict__ out, int b_base) {
  __shared__ __align__(16) unsigned short As[128 * 32];
  __shared__ __align__(16) unsigned short Bs[128 * 32];
  int b = b_base + blockIdx.z;
  const unsigned short* xb = xbT + (size_t)blockIdx.z * TT * CIN;
  int row0 = blockIdx.x * 128;
  int t0 = blockIdx.y * 128;
  int tid = threadIdx.x;
  int lane = tid & 63, wid = tid >> 6;
  int wr = wid >> 1, wc = wid & 1;
  int l15 = lane & 15, kg = lane >> 4;
  int rs = tid >> 2, cch = tid & 3;

  const unsigned short* aw[2];
  const unsigned short* bw[2][3];
#pragma unroll
  for (int h = 0; h < 2; ++h) {
    int r = rs + h * 64;
    int cs = cch ^ ((r >> 1) & 3);
    aw[h] = Wb + (size_t)(row0 + r) * KTOT + cs * 8;
    int t = t0 + r;
    float dv = d[(size_t)b * TT + t];
    int dil = (int)dv; if (dil < 1) dil = 1;
    int p = t - dil; if (p < 0) p = -p; p &= (TT - 1);
    int f0 = t + dil;
    int f = (f0 >= TT) ? (TT - 1 - (f0 & (TT - 1))) : f0;
    bw[h][0] = xb + (size_t)p * CIN + cs * 8;
    bw[h][1] = xb + (size_t)t * CIN + cs * 8;
    bw[h][2] = xb + (size_t)f * CIN + cs * 8;
  }
  unsigned short* aDst[2];
  unsigned short* bDst[2];
#pragma unroll
  for (int h = 0; h < 2; ++h) {
    aDst[h] = As + h * 2048 + wid * 512;
    bDst[h] = Bs + h * 2048 + wid * 512;
  }
  int aoff[4], boff[4];
#pragma unroll
  for (int mi = 0; mi < 4; ++mi) {
    int r = wr * 64 + mi * 16 + l15;
    aoff[mi] = r * 32 + (kg ^ ((r >> 1) & 3)) * 8;
  }
#pragma unroll
  for (int ni = 0; ni < 4; ++ni) {
    int r = wc * 64 + ni * 16 + l15;
    boff[ni] = r * 32 + (kg ^ ((r >> 1) & 3)) * 8;
  }
  f32x4 acc[4][4] = {};
#pragma unroll
  for (int s = 0; s < 3; ++s) {
    for (int kt = 0; kt < 16; ++kt) {
      int koff = kt * 32;
#pragma unroll
      for (int h = 0; h < 2; ++h) {
        GLD16(aw[h] + s * CIN + koff, aDst[h]);
        GLD16(bw[h][s] + koff, bDst[h]);
      }
      __syncthreads();
      bf16x8 af[4], bf[4];
#pragma unroll
      for (int mi = 0; mi < 4; ++mi) af[mi] = *(const bf16x8*)(&As[aoff[mi]]);
#pragma unroll
      for (int ni = 0; ni < 4; ++ni) bf[ni] = *(const bf16x8*)(&Bs[boff[ni]]);
#pragma unroll
      for (int mi = 0; mi < 4; ++mi)
#pragma unroll
        for (int ni = 0; ni < 4; ++ni)
          acc[mi][ni] = MFMA(af[mi], bf[ni], acc[mi][ni]);
      __syncthreads();
    }
  }
  float* ob = out + (size_t)b * COUT * TT;
#pragma unroll
  for (int mi = 0; mi < 4; ++mi) {
    int m0 = row0 + wr * 64 + mi * 16 + kg * 4;
#pragma unroll
    for (int ni = 0; ni < 4; ++ni) {
      int t = t0 + wc * 64 + ni * 16 + l15;
#pragma unroll
      for (int j = 0; j < 4; ++j) {
        ob[(size_t)(m0 + j) * TT + t] = acc[mi][ni][j] + bias[m0 + j];
      }
    }
  }
}

extern "C" void kernel_launch(void* const* d_in, const int* in_sizes, int n_in,
                              void* d_out, int out_size, void* d_ws, size_t ws_size,
                              hipStream_t stream) {
  const float* x  = (const float*)d_in[0];
  const float* d  = (const float*)d_in[1];
  const float* W0 = (const float*)d_in[2];
  const float* b0 = (const float*)d_in[3];
  const float* W1 = (const float*)d_in[4];
  const float* W2 = (const float*)d_in[5];
  float* out = (float*)d_out;

  char* ws = (char*)d_ws;
  unsigned short* Wb  = (unsigned short*)ws;                       // 1.5 MiB
  unsigned short* xbT = (unsigned short*)(ws + (2u << 20));        // 8 MiB per batch
  const size_t SZ_XBT1 = (size_t)TT * CIN * 2;
  const size_t NEED_FULL = (size_t)(2u << 20) + (size_t)NB * SZ_XBT1;  // ~66 MiB
  const size_t NEED_MIN  = (size_t)(2u << 20) + SZ_XBT1;               // ~10 MiB

  if (ws_size >= NEED_MIN) {
    k_convert_w<<<dim3(1024, 3), 256, 0, stream>>>(W0, W1, W2, Wb);
    if (ws_size >= NEED_FULL) {
      k_transpose<<<dim3(TT / 64, CIN / 64, NB), 256, 0, stream>>>(x, xbT, 0);
      // fast kernel handles blocks with uniform dil==1; slow kernel the rest
      k_gemm_w4<<<dim3(NB, (TT / 256) * (COUT / 256), 1), 256, 0, stream>>>(
          Wb, xbT, d, b0, out);
      k_gemm256<<<dim3(NB, (TT / 256) * (COUT / 256), 1), 512, 0, stream>>>(
          Wb, xbT, d, b0, out);
    } else {
      for (int b = 0; b < NB; ++b) {
        k_transpose<<<dim3(TT / 64, CIN / 64, 1), 256, 0, stream>>>(x, xbT, b);
        k_gemm<<<dim3(COUT / 128, TT / 128, 1), 256, 0, stream>>>(Wb, xbT, d, b0, out, b);
      }
    }
  } else {
    for (int b = 0; b < NB; ++b) {
      k_transpose<<<dim3(TT / 64, CIN / 64, 1), 256, 0, stream>>>(x, xbT, b);
      k_gemm<<<dim3(COUT / 128, TT / 128, 1), 256, 0, stream>>>(Wb, xbT, d, b0, out, b);
    }
  }
}

// Round 11
// 271.210 us; speedup vs baseline: 1.7759x; 1.7759x over previous
//
#include <hip/hip_runtime.h>

#define TT 8192
#define CIN 512
#define COUT 512
#define NB 8
#define KTOT 1536   // 3 * CIN
#define NT 24       // K tiles of 64

typedef __attribute__((ext_vector_type(4))) float f32x4;
typedef __attribute__((ext_vector_type(8))) short bf16x8;
typedef __attribute__((ext_vector_type(8))) unsigned short u16x8;

#define GLD16(g, l) __builtin_amdgcn_global_load_lds(                      \
    (const __attribute__((address_space(1))) void*)(g),                    \
    (__attribute__((address_space(3))) void*)(l), 16, 0, 0)

#define CFENCE() asm volatile("" ::: "memory")
#define SBAR() do { CFENCE(); __builtin_amdgcn_s_barrier(); CFENCE(); } while (0)
#define VMCNT20() asm volatile("s_waitcnt vmcnt(20)" ::: "memory")
#define VMCNT16() asm volatile("s_waitcnt vmcnt(16)" ::: "memory")
#define VMCNT0() asm volatile("s_waitcnt vmcnt(0)" ::: "memory")
#define LGKM0() asm volatile("s_waitcnt lgkmcnt(0)" ::: "memory")
#define MFMA(a_, b_, c_) __builtin_amdgcn_mfma_f32_16x16x32_bf16((a_), (b_), (c_), 0, 0, 0)

__device__ inline unsigned short f2bf(float f) {
  union { float f; unsigned int u; } v; v.f = f;
  unsigned int u = v.u;
  unsigned int r = (u + 0x7FFFu + ((u >> 16) & 1u)) >> 16;  // RNE
  return (unsigned short)r;
}

__global__ void k_convert_w(const float* __restrict__ W0, const float* __restrict__ W1,
                            const float* __restrict__ W2, unsigned short* __restrict__ Wb) {
  int i = blockIdx.x * 256 + threadIdx.x;
  if (i >= COUT * CIN) return;
  const float* Ws = blockIdx.y == 0 ? W0 : (blockIdx.y == 1 ? W1 : W2);
  int o = i >> 9, c = i & 511;
  Wb[(size_t)o * KTOT + blockIdx.y * CIN + c] = f2bf(Ws[i]);
}

// x (B, C, T) fp32 -> xbT (T, C) bf16 per batch. grid (T/64, C/64, nb), block 256
__global__ void k_transpose(const float* __restrict__ x, unsigned short* __restrict__ xbT,
                            int b_base) {
  int b = b_base + blockIdx.z;
  const float* xb = x + (size_t)b * CIN * TT;
  unsigned short* xo = xbT + (size_t)blockIdx.z * TT * CIN;
  __shared__ float tile[64][65];
  int t0 = blockIdx.x * 64, c0 = blockIdx.y * 64;
  int tid = threadIdx.x;
#pragma unroll
  for (int it = 0; it < 16; ++it) {
    int L = it * 256 + tid;
    int c = L >> 6, t = L & 63;
    tile[c][t] = xb[(size_t)(c0 + c) * TT + (t0 + t)];
  }
  __syncthreads();
#pragma unroll
  for (int it = 0; it < 16; ++it) {
    int L = it * 256 + tid;
    int t = L >> 6, c = L & 63;
    xo[(size_t)(t0 + t) * CIN + (c0 + c)] = f2bf(tile[c][t]);
  }
}

// ------------- 256x256 fused gather-GEMM: A direct-to-register, B via LDS -------------
// grid (8, 64), block 512 (8 waves, 2M x 4N). id%8 = batch -> XCD.
// A (Wb, L2/L1-hot, ungathered) loads global->VGPR: lane reads row
// row0+wr*128+mh*64+mi*16+l15, k-chunk kg+4*kh -- identical k-permutation to the
// LDS path (verified algebraically), so A/B chunk match is preserved.
// LDS holds only B (2 x 32 KB double buffer). Per tile LDS reads drop 192->64 KB.
__global__ __launch_bounds__(512) void k_gemm256(
    const unsigned short* __restrict__ Wb, const unsigned short* __restrict__ xbT,
    const float* __restrict__ d, const float* __restrict__ bias,
    float* __restrict__ out) {
  __shared__ __align__(16) unsigned short Bs[2][256 * 64];  // 64 KiB
  const int b = blockIdx.x;                    // batch = id%8 -> XCD
  const int t0 = (blockIdx.y >> 1) * 256;      // t-tile
  const int row0 = (blockIdx.y & 1) * 256;     // M-tile
  const unsigned short* xb = xbT + (size_t)b * TT * CIN;
  const int tid = threadIdx.x;
  const int lane = tid & 63, wid = tid >> 6;
  const int wr = wid >> 2, wc = wid & 3;
  const int l15 = lane & 15, kg = lane >> 4;

  // ---- B staging (gather): round j covers row r = j*64 + (tid>>3), chunk tid&7
  const int srow = tid >> 3;
  const int cSrc8 = (((tid & 7) ^ ((tid >> 4) & 7))) * 8;  // swizzled 16B chunk
  int bOff[3][4];     // xbT ushort offsets per segment, add (tc&7)*64
#pragma unroll
  for (int j = 0; j < 4; ++j) {
    int t = t0 + j * 64 + srow;
    float dv = d[(size_t)b * TT + t];
    int dil = (int)dv; if (dil < 1) dil = 1;
    int p = t - dil; if (p < 0) p = -p; p &= (TT - 1);
    int f0 = t + dil;
    int f = (f0 >= TT) ? (TT - 1 - (f0 & (TT - 1))) : f0;
    bOff[0][j] = p * CIN + cSrc8;
    bOff[1][j] = t * CIN + cSrc8;
    bOff[2][j] = f * CIN + cSrc8;
  }

  // ---- B fragment read offsets (swizzled LDS), as r9
  const int s7 = l15 >> 1;
  const int chunk0 = (kg ^ (s7 & 3)) + (s7 & 4);
  const int dK = (l15 & 8) ? -32 : 32;
  int bRd[2][2];
#pragma unroll
  for (int nh = 0; nh < 2; ++nh)
#pragma unroll
    for (int ni = 0; ni < 2; ++ni)
      bRd[nh][ni] = (wc * 64 + nh * 32 + ni * 16 + l15) * 64 + chunk0 * 8;

  // ---- A direct-global fragment offsets (ushort units): + tc*64 + kh*32
  int aOffA[2][4];
#pragma unroll
  for (int mh = 0; mh < 2; ++mh)
#pragma unroll
    for (int mi = 0; mi < 4; ++mi)
      aOffA[mh][mi] = (row0 + wr * 128 + mh * 64 + mi * 16 + l15) * KTOT + kg * 8;

#define STAGE_B2(tc_, buf_, jp_) do {                                         \
    _Pragma("unroll") for (int j = 2 * (jp_); j < 2 * (jp_) + 2; ++j)         \
      GLD16(xb + bOff[(tc_) >> 3][j] + ((tc_) & 7) * 64,                      \
            &Bs[buf_][j * 4096 + wid * 512]);                                 \
  } while (0)
#define LOAD_A(mh_, tc_) do {                                                 \
    _Pragma("unroll") for (int mi = 0; mi < 4; ++mi) {                        \
      af[mh_][mi][0] = *(const bf16x8*)(Wb + aOffA[mh_][mi] + (tc_) * 64);    \
      af[mh_][mi][1] = *(const bf16x8*)(Wb + aOffA[mh_][mi] + (tc_) * 64 + 32);\
    }                                                                         \
  } while (0)

  bf16x8 af[2][4][2], bfr[2][2];
  f32x4 acc[8][4] = {};

  // prologue: B(0)->Bs[0], B(1)->Bs[1]; af(0) direct loads; drain B(0) only
  STAGE_B2(0, 0, 0); STAGE_B2(0, 0, 1);
  STAGE_B2(1, 1, 0); STAGE_B2(1, 1, 1);
  LOAD_A(0, 0); LOAD_A(1, 0);
  VMCNT20();   // FIFO: B0(4) B1(4) af(16) -> <=20 drains B(0)
  SBAR();

  // per tile: {bf h0; MFMA mh0xh0; MFMA mh1xh0; bf h1; MFMA mh0xh1; issue afA(t+1);
  //  MFMA mh1xh1; issue afB(t+1); LGKM0; BAR; stage B(t+2); vmcnt(20); BAR}
#pragma unroll 2
  for (int tc = 0; tc < NT; ++tc) {
    const int cur = tc & 1;
    // bf h0
#pragma unroll
    for (int ni = 0; ni < 2; ++ni) {
      bfr[ni][0] = *(const bf16x8*)&Bs[cur][bRd[0][ni]];
      bfr[ni][1] = *(const bf16x8*)&Bs[cur][bRd[0][ni] + dK];
    }
    __builtin_amdgcn_s_setprio(1);
#pragma unroll
    for (int mi = 0; mi < 4; ++mi)
#pragma unroll
      for (int ni = 0; ni < 2; ++ni) {
        acc[mi][ni] = MFMA(af[0][mi][0], bfr[ni][0], acc[mi][ni]);
        acc[mi][ni] = MFMA(af[0][mi][1], bfr[ni][1], acc[mi][ni]);
      }
    __builtin_amdgcn_s_setprio(0);
    __builtin_amdgcn_s_setprio(1);
#pragma unroll
    for (int mi = 0; mi < 4; ++mi)
#pragma unroll
      for (int ni = 0; ni < 2; ++ni) {
        acc[4 + mi][ni] = MFMA(af[1][mi][0], bfr[ni][0], acc[4 + mi][ni]);
        acc[4 + mi][ni] = MFMA(af[1][mi][1], bfr[ni][1], acc[4 + mi][ni]);
      }
    __builtin_amdgcn_s_setprio(0);
    // bf h1 (recycle bfr)
#pragma unroll
    for (int ni = 0; ni < 2; ++ni) {
      bfr[ni][0] = *(const bf16x8*)&Bs[cur][bRd[1][ni]];
      bfr[ni][1] = *(const bf16x8*)&Bs[cur][bRd[1][ni] + dK];
    }
    __builtin_amdgcn_s_setprio(1);
#pragma unroll
    for (int mi = 0; mi < 4; ++mi)
#pragma unroll
      for (int ni = 0; ni < 2; ++ni) {
        acc[mi][2 + ni] = MFMA(af[0][mi][0], bfr[ni][0], acc[mi][2 + ni]);
        acc[mi][2 + ni] = MFMA(af[0][mi][1], bfr[ni][1], acc[mi][2 + ni]);
      }
    __builtin_amdgcn_s_setprio(0);
    if (tc + 1 < NT) LOAD_A(0, tc + 1);   // af[0] dead after mh0 x h1
    __builtin_amdgcn_s_setprio(1);
#pragma unroll
    for (int mi = 0; mi < 4; ++mi)
#pragma unroll
      for (int ni = 0; ni < 2; ++ni) {
        acc[4 + mi][2 + ni] = MFMA(af[1][mi][0], bfr[ni][0], acc[4 + mi][2 + ni]);
        acc[4 + mi][2 + ni] = MFMA(af[1][mi][1], bfr[ni][1], acc[4 + mi][2 + ni]);
      }
    __builtin_amdgcn_s_setprio(0);
    if (tc + 1 < NT) LOAD_A(1, tc + 1);   // af[1] dead after mh1 x h1
    LGKM0();   // all this wave's Bs[cur] reads complete
    SBAR();    // cross-wave: Bs[cur] reusable
    if (tc + 2 < NT) { STAGE_B2(tc + 2, cur, 0); STAGE_B2(tc + 2, cur, 1); }
    // drain B(tc+1) (oldest); keep af(tc+1) + B(tc+2) in flight
    if (tc + 2 < NT) { VMCNT20(); }       // B(t+1)4 | afA8 afB8 B(t+2)4
    else if (tc + 1 < NT) { VMCNT16(); }  // B(t+1)4 | afA8 afB8
    SBAR();
  }

  // epilogue: bias + fp32 store
  float* ob = out + (size_t)b * COUT * TT;
#pragma unroll
  for (int mh = 0; mh < 2; ++mh)
#pragma unroll
    for (int mi = 0; mi < 4; ++mi) {
      int m0 = row0 + wr * 128 + mh * 64 + mi * 16 + kg * 4;
#pragma unroll
      for (int nh = 0; nh < 2; ++nh)
#pragma unroll
        for (int ni = 0; ni < 2; ++ni) {
          int t = t0 + wc * 64 + nh * 32 + ni * 16 + l15;
          f32x4 v = acc[mh * 4 + mi][nh * 2 + ni];
#pragma unroll
          for (int j = 0; j < 4; ++j)
            ob[(size_t)(m0 + j) * TT + t] = v[j] + bias[m0 + j];
        }
    }
}

// ---------------- fallback 128x128 (small ws) ----------------
__global__ __launch_bounds__(256) void k_gemm(
    const unsigned short* __restrict__ Wb, const unsigned short* __restrict__ xbT,
    const float* __restrict__ d, const float* __restrict__ bias,
    float* __restrict__ out, int b_base) {
  __shared__ __align__(16) unsigned short As[128 * 32];
  __shared__ __align__(16) unsigned short Bs[128 * 32];
  int b = b_base + blockIdx.z;
  const unsigned short* xb = xbT + (size_t)blockIdx.z * TT * CIN;
  int row0 = blockIdx.x * 128;
  int t0 = blockIdx.y * 128;
  int tid = threadIdx.x;
  int lane = tid & 63, wid = tid >> 6;
  int wr = wid >> 1, wc = wid & 1;
  int l15 = lane & 15, kg = lane >> 4;
  int rs = tid >> 2, cch = tid & 3;

  const unsigned short* aw[2];
  const unsigned short* bw[2][3];
#pragma unroll
  for (int h = 0; h < 2; ++h) {
    int r = rs + h * 64;
    int cs = cch ^ ((r >> 1) & 3);
    aw[h] = Wb + (size_t)(row0 + r) * KTOT + cs * 8;
    int t = t0 + r;
    float dv = d[(size_t)b * TT + t];
    int dil = (int)dv; if (dil < 1) dil = 1;
    int p = t - dil; if (p < 0) p = -p; p &= (TT - 1);
    int f0 = t + dil;
    int f = (f0 >= TT) ? (TT - 1 - (f0 & (TT - 1))) : f0;
    bw[h][0] = xb + (size_t)p * CIN + cs * 8;
    bw[h][1] = xb + (size_t)t * CIN + cs * 8;
    bw[h][2] = xb + (size_t)f * CIN + cs * 8;
  }
  unsigned short* aDst[2];
  unsigned short* bDst[2];
#pragma unroll
  for (int h = 0; h < 2; ++h) {
    aDst[h] = As + h * 2048 + wid * 512;
    bDst[h] = Bs + h * 2048 + wid * 512;
  }
  int aoff[4], boff[4];
#pragma unroll
  for (int mi = 0; mi < 4; ++mi) {
    int r = wr * 64 + mi * 16 + l15;
    aoff[mi] = r * 32 + (kg ^ ((r >> 1) & 3)) * 8;
  }
#pragma unroll
  for (int ni = 0; ni < 4; ++ni) {
    int r = wc * 64 + ni * 16 + l15;
    boff[ni] = r * 32 + (kg ^ ((r >> 1) & 3)) * 8;
  }
  f32x4 acc[4][4] = {};
#pragma unroll
  for (int s = 0; s < 3; ++s) {
    for (int kt = 0; kt < 16; ++kt) {
      int koff = kt * 32;
#pragma unroll
      for (int h = 0; h < 2; ++h) {
        GLD16(aw[h] + s * CIN + koff, aDst[h]);
        GLD16(bw[h][s] + koff, bDst[h]);
      }
      __syncthreads();
      bf16x8 af[4], bf[4];
#pragma unroll
      for (int mi = 0; mi < 4; ++mi) af[mi] = *(const bf16x8*)(&As[aoff[mi]]);
#pragma unroll
      for (int ni = 0; ni < 4; ++ni) bf[ni] = *(const bf16x8*)(&Bs[boff[ni]]);
#pragma unroll
      for (int mi = 0; mi < 4; ++mi)
#pragma unroll
        for (int ni = 0; ni < 4; ++ni)
          acc[mi][ni] = MFMA(af[mi], bf[ni], acc[mi][ni]);
      __syncthreads();
    }
  }
  float* ob = out + (size_t)b * COUT * TT;
#pragma unroll
  for (int mi = 0; mi < 4; ++mi) {
    int m0 = row0 + wr * 64 + mi * 16 + kg * 4;
#pragma unroll
    for (int ni = 0; ni < 4; ++ni) {
      int t = t0 + wc * 64 + ni * 16 + l15;
#pragma unroll
      for (int j = 0; j < 4; ++j) {
        ob[(size_t)(m0 + j) * TT + t] = acc[mi][ni][j] + bias[m0 + j];
      }
    }
  }
}

extern "C" void kernel_launch(void* const* d_in, const int* in_sizes, int n_in,
                              void* d_out, int out_size, void* d_ws, size_t ws_size,
                              hipStream_t stream) {
  const float* x  = (const float*)d_in[0];
  const float* d  = (const float*)d_in[1];
  const float* W0 = (const float*)d_in[2];
  const float* b0 = (const float*)d_in[3];
  const float* W1 = (const float*)d_in[4];
  const float* W2 = (const float*)d_in[5];
  float* out = (float*)d_out;

  char* ws = (char*)d_ws;
  unsigned short* Wb  = (unsigned short*)ws;                       // 1.5 MiB
  unsigned short* xbT = (unsigned short*)(ws + (2u << 20));        // 8 MiB per batch
  const size_t SZ_XBT1 = (size_t)TT * CIN * 2;
  const size_t NEED_FULL = (size_t)(2u << 20) + (size_t)NB * SZ_XBT1;  // ~66 MiB
  const size_t NEED_MIN  = (size_t)(2u << 20) + SZ_XBT1;               // ~10 MiB

  if (ws_size >= NEED_MIN) {
    k_convert_w<<<dim3(1024, 3), 256, 0, stream>>>(W0, W1, W2, Wb);
    if (ws_size >= NEED_FULL) {
      k_transpose<<<dim3(TT / 64, CIN / 64, NB), 256, 0, stream>>>(x, xbT, 0);
      k_gemm256<<<dim3(NB, (TT / 256) * (COUT / 256), 1), 512, 0, stream>>>(
          Wb, xbT, d, b0, out);
    } else {
      for (int b = 0; b < NB; ++b) {
        k_transpose<<<dim3(TT / 64, CIN / 64, 1), 256, 0, stream>>>(x, xbT, b);
        k_gemm<<<dim3(COUT / 128, TT / 128, 1), 256, 0, stream>>>(Wb, xbT, d, b0, out, b);
      }
    }
  } else {
    for (int b = 0; b < NB; ++b) {
      k_transpose<<<dim3(TT / 64, CIN / 64, 1), 256, 0, stream>>>(x, xbT, b);
      k_gemm<<<dim3(COUT / 128, TT / 128, 1), 256, 0, stream>>>(Wb, xbT, d, b0, out, b);
    }
  }
}

// Round 12
// 142.221 us; speedup vs baseline: 3.3865x; 1.9070x over previous
//
#include <hip/hip_runtime.h>

#define TT 8192
#define CIN 512
#define COUT 512
#define NB 8
#define KTOT 1536   // 3 * CIN
#define NT 24       // K tiles of 64

typedef __attribute__((ext_vector_type(4))) float f32x4;
typedef __attribute__((ext_vector_type(8))) short bf16x8;
typedef __attribute__((ext_vector_type(8))) unsigned short u16x8;

#define GLD16(g, l) __builtin_amdgcn_global_load_lds(                      \
    (const __attribute__((address_space(1))) void*)(g),                    \
    (__attribute__((address_space(3))) void*)(l), 16, 0, 0)

#define CFENCE() asm volatile("" ::: "memory")
#define SBAR() do { CFENCE(); __builtin_amdgcn_s_barrier(); CFENCE(); } while (0)
#define VMCNT6() asm volatile("s_waitcnt vmcnt(6)" ::: "memory")
#define VMCNT2() asm volatile("s_waitcnt vmcnt(2)" ::: "memory")
#define VMCNT0() asm volatile("s_waitcnt vmcnt(0)" ::: "memory")
#define LGKM0() asm volatile("s_waitcnt lgkmcnt(0)" ::: "memory")
#define MFMA(a_, b_, c_) __builtin_amdgcn_mfma_f32_16x16x32_bf16((a_), (b_), (c_), 0, 0, 0)

__device__ inline unsigned short f2bf(float f) {
  union { float f; unsigned int u; } v; v.f = f;
  unsigned int u = v.u;
  unsigned int r = (u + 0x7FFFu + ((u >> 16) & 1u)) >> 16;  // RNE
  return (unsigned short)r;
}

__global__ void k_convert_w(const float* __restrict__ W0, const float* __restrict__ W1,
                            const float* __restrict__ W2, unsigned short* __restrict__ Wb) {
  int i = blockIdx.x * 256 + threadIdx.x;
  if (i >= COUT * CIN) return;
  const float* Ws = blockIdx.y == 0 ? W0 : (blockIdx.y == 1 ? W1 : W2);
  int o = i >> 9, c = i & 511;
  Wb[(size_t)o * KTOT + blockIdx.y * CIN + c] = f2bf(Ws[i]);
}

// x (B, C, T) fp32 -> xbT (T, C) bf16 per batch. grid (T/64, C/64, nb), block 256
__global__ void k_transpose(const float* __restrict__ x, unsigned short* __restrict__ xbT,
                            int b_base) {
  int b = b_base + blockIdx.z;
  const float* xb = x + (size_t)b * CIN * TT;
  unsigned short* xo = xbT + (size_t)blockIdx.z * TT * CIN;
  __shared__ float tile[64][65];
  int t0 = blockIdx.x * 64, c0 = blockIdx.y * 64;
  int tid = threadIdx.x;
#pragma unroll
  for (int it = 0; it < 16; ++it) {
    int L = it * 256 + tid;
    int c = L >> 6, t = L & 63;
    tile[c][t] = xb[(size_t)(c0 + c) * TT + (t0 + t)];
  }
  __syncthreads();
#pragma unroll
  for (int it = 0; it < 16; ++it) {
    int L = it * 256 + tid;
    int t = L >> 6, c = L & 63;
    xo[(size_t)(t0 + t) * CIN + (c0 + c)] = f2bf(tile[c][t]);
  }
}

// -------- 256x256 fused gather-GEMM, half-publish pipeline (2 barriers/tile) --------
// grid (8, 64), block 512 (8 waves, 2M x 4N). id%8 = batch -> XCD.
// Tile t: PH0{read af(mh0)+bf0+bf1; stage B(t+1)+A-g0(t+1); MFMA Q00+Q01;
//             lgkm0; vmcnt(6) [drain A-g1(t)]; BAR = publish A-mh1(t)}
//         PH2{read af(mh1); stage A-g1(t+1); MFMA Q10+Q11;
//             lgkm0; vmcnt(2) [drain B(t+1)+A-g0(t+1), keep A-g1(t+1)]; BAR}
// A-g0 = stage rounds {0,2} (rows 0-63,128-191 = both wr's mh0); A-g1 = rounds {1,3}.
__global__ __launch_bounds__(512) void k_gemm256(
    const unsigned short* __restrict__ Wb, const unsigned short* __restrict__ xbT,
    const float* __restrict__ d, const float* __restrict__ bias,
    float* __restrict__ out) {
  __shared__ __align__(16) unsigned short As[2][256 * 64];
  __shared__ __align__(16) unsigned short Bs[2][256 * 64];
  const int b = blockIdx.x;                    // batch = id%8 -> XCD
  const int t0 = (blockIdx.y >> 1) * 256;      // t-tile
  const int row0 = (blockIdx.y & 1) * 256;     // M-tile
  const unsigned short* xb = xbT + (size_t)b * TT * CIN;
  const int tid = threadIdx.x;
  const int lane = tid & 63, wid = tid >> 6;
  const int wr = wid >> 2, wc = wid & 3;
  const int l15 = lane & 15, kg = lane >> 4;

  // staging sources: round j covers row r = j*64 + (tid>>3), chunk slot tid&7
  const int srow = tid >> 3;
  const int cSrc8 = (((tid & 7) ^ ((tid >> 4) & 7))) * 8;  // swizzled 16B chunk
  int aOff[4];        // Wb ushort offsets, add tc*64
  int bOff[3][4];     // xbT ushort offsets per segment, add (tc&7)*64
#pragma unroll
  for (int j = 0; j < 4; ++j) {
    int r = j * 64 + srow;
    aOff[j] = (row0 + r) * KTOT + cSrc8;
    int t = t0 + r;
    float dv = d[(size_t)b * TT + t];
    int dil = (int)dv; if (dil < 1) dil = 1;
    int p = t - dil; if (p < 0) p = -p; p &= (TT - 1);
    int f0 = t + dil;
    int f = (f0 >= TT) ? (TT - 1 - (f0 & (TT - 1))) : f0;
    bOff[0][j] = p * CIN + cSrc8;
    bOff[1][j] = t * CIN + cSrc8;
    bOff[2][j] = f * CIN + cSrc8;
  }

  // fragment read offsets (swizzled): row r, chunk (kh*4+kg) ^ ((r>>1)&7)
  const int s7 = l15 >> 1;
  const int chunk0 = (kg ^ (s7 & 3)) + (s7 & 4);
  const int dK = (l15 & 8) ? -32 : 32;  // ushort delta for kh=1
  int aRd[2][4], bRd[2][2];
#pragma unroll
  for (int mh = 0; mh < 2; ++mh)
#pragma unroll
    for (int mi = 0; mi < 4; ++mi)
      aRd[mh][mi] = (wr * 128 + mh * 64 + mi * 16 + l15) * 64 + chunk0 * 8;
#pragma unroll
  for (int nh = 0; nh < 2; ++nh)
#pragma unroll
    for (int ni = 0; ni < 2; ++ni)
      bRd[nh][ni] = (wc * 64 + nh * 32 + ni * 16 + l15) * 64 + chunk0 * 8;

#define STAGE_A_G0(tc_, buf_) do {                                            \
    GLD16(Wb + aOff[0] + (tc_) * 64, &As[buf_][0 * 4096 + wid * 512]);        \
    GLD16(Wb + aOff[2] + (tc_) * 64, &As[buf_][2 * 4096 + wid * 512]);        \
  } while (0)
#define STAGE_A_G1(tc_, buf_) do {                                            \
    GLD16(Wb + aOff[1] + (tc_) * 64, &As[buf_][1 * 4096 + wid * 512]);        \
    GLD16(Wb + aOff[3] + (tc_) * 64, &As[buf_][3 * 4096 + wid * 512]);        \
  } while (0)
#define STAGE_B4(tc_, buf_) do {                                              \
    _Pragma("unroll") for (int j = 0; j < 4; ++j)                             \
      GLD16(xb + bOff[(tc_) >> 3][j] + ((tc_) & 7) * 64,                      \
            &Bs[buf_][j * 4096 + wid * 512]);                                 \
  } while (0)

  // prologue: tile 0 fully staged; full drain once; steady state starts at tc=0
  STAGE_B4(0, 0); STAGE_A_G0(0, 0); STAGE_A_G1(0, 0);
  VMCNT0();
  SBAR();

  bf16x8 af[4][2], bf0[2][2], bf1[2][2];
  f32x4 acc[8][4] = {};

#pragma unroll 2
  for (int tc = 0; tc < NT; ++tc) {
    const int cur = tc & 1;
    // ---------- PH0: frag reads (af mh0, bf both halves); stage B+A-g0 (t+1)
#pragma unroll
    for (int mi = 0; mi < 4; ++mi) {
      af[mi][0] = *(const bf16x8*)&As[cur][aRd[0][mi]];
      af[mi][1] = *(const bf16x8*)&As[cur][aRd[0][mi] + dK];
    }
#pragma unroll
    for (int ni = 0; ni < 2; ++ni) {
      bf0[ni][0] = *(const bf16x8*)&Bs[cur][bRd[0][ni]];
      bf0[ni][1] = *(const bf16x8*)&Bs[cur][bRd[0][ni] + dK];
      bf1[ni][0] = *(const bf16x8*)&Bs[cur][bRd[1][ni]];
      bf1[ni][1] = *(const bf16x8*)&Bs[cur][bRd[1][ni] + dK];
    }
    if (tc + 1 < NT) { STAGE_B4(tc + 1, cur ^ 1); STAGE_A_G0(tc + 1, cur ^ 1); }
    __builtin_amdgcn_s_setprio(1);
#pragma unroll
    for (int mi = 0; mi < 4; ++mi)
#pragma unroll
      for (int ni = 0; ni < 2; ++ni) {
        acc[mi][ni] = MFMA(af[mi][0], bf0[ni][0], acc[mi][ni]);
        acc[mi][ni] = MFMA(af[mi][1], bf0[ni][1], acc[mi][ni]);
        acc[mi][2 + ni] = MFMA(af[mi][0], bf1[ni][0], acc[mi][2 + ni]);
        acc[mi][2 + ni] = MFMA(af[mi][1], bf1[ni][1], acc[mi][2 + ni]);
      }
    __builtin_amdgcn_s_setprio(0);
    LGKM0();                              // own af(mh0)+bf reads done
    if (tc + 1 < NT) { VMCNT6(); }        // drain A-g1(t); keep PH0 stages
    else { VMCNT0(); }
    SBAR();                               // MID: publishes A-mh1(t)
    // ---------- PH2: frag reads (af mh1); stage A-g1(t+1)
#pragma unroll
    for (int mi = 0; mi < 4; ++mi) {
      af[mi][0] = *(const bf16x8*)&As[cur][aRd[1][mi]];
      af[mi][1] = *(const bf16x8*)&As[cur][aRd[1][mi] + dK];
    }
    if (tc + 1 < NT) STAGE_A_G1(tc + 1, cur ^ 1);
    __builtin_amdgcn_s_setprio(1);
#pragma unroll
    for (int mi = 0; mi < 4; ++mi)
#pragma unroll
      for (int ni = 0; ni < 2; ++ni) {
        acc[4 + mi][ni] = MFMA(af[mi][0], bf0[ni][0], acc[4 + mi][ni]);
        acc[4 + mi][ni] = MFMA(af[mi][1], bf0[ni][1], acc[4 + mi][ni]);
        acc[4 + mi][2 + ni] = MFMA(af[mi][0], bf1[ni][0], acc[4 + mi][2 + ni]);
        acc[4 + mi][2 + ni] = MFMA(af[mi][1], bf1[ni][1], acc[4 + mi][2 + ni]);
      }
    __builtin_amdgcn_s_setprio(0);
    LGKM0();                              // own af(mh1) reads done (WAR vs t+1 writes)
    if (tc + 1 < NT) { VMCNT2(); }        // drain B(t+1)+A-g0(t+1); keep A-g1(t+1)
    SBAR();                               // END: publishes B(t+1)+A-g0(t+1)
  }

  // epilogue: bias + fp32 store
  float* ob = out + (size_t)b * COUT * TT;
#pragma unroll
  for (int mh = 0; mh < 2; ++mh)
#pragma unroll
    for (int mi = 0; mi < 4; ++mi) {
      int m0 = row0 + wr * 128 + mh * 64 + mi * 16 + kg * 4;
#pragma unroll
      for (int nh = 0; nh < 2; ++nh)
#pragma unroll
        for (int ni = 0; ni < 2; ++ni) {
          int t = t0 + wc * 64 + nh * 32 + ni * 16 + l15;
          f32x4 v = acc[mh * 4 + mi][nh * 2 + ni];
#pragma unroll
          for (int j = 0; j < 4; ++j)
            ob[(size_t)(m0 + j) * TT + t] = v[j] + bias[m0 + j];
        }
    }
}

// ---------------- fallback 128x128 (small ws) ----------------
__global__ __launch_bounds__(256) void k_gemm(
    const unsigned short* __restrict__ Wb, const unsigned short* __restrict__ xbT,
    const float* __restrict__ d, const float* __restrict__ bias,
    float* __restrict__ out, int b_base) {
  __shared__ __align__(16) unsigned short As[128 * 32];
  __shared__ __align__(16) unsigned short Bs[128 * 32];
  int b = b_base + blockIdx.z;
  const unsigned short* xb = xbT + (size_t)blockIdx.z * TT * CIN;
  int row0 = blockIdx.x * 128;
  int t0 = blockIdx.y * 128;
  int tid = threadIdx.x;
  int lane = tid & 63, wid = tid >> 6;
  int wr = wid >> 1, wc = wid & 1;
  int l15 = lane & 15, kg = lane >> 4;
  int rs = tid >> 2, cch = tid & 3;

  const unsigned short* aw[2];
  const unsigned short* bw[2][3];
#pragma unroll
  for (int h = 0; h < 2; ++h) {
    int r = rs + h * 64;
    int cs = cch ^ ((r >> 1) & 3);
    aw[h] = Wb + (size_t)(row0 + r) * KTOT + cs * 8;
    int t = t0 + r;
    float dv = d[(size_t)b * TT + t];
    int dil = (int)dv; if (dil < 1) dil = 1;
    int p = t - dil; if (p < 0) p = -p; p &= (TT - 1);
    int f0 = t + dil;
    int f = (f0 >= TT) ? (TT - 1 - (f0 & (TT - 1))) : f0;
    bw[h][0] = xb + (size_t)p * CIN + cs * 8;
    bw[h][1] = xb + (size_t)t * CIN + cs * 8;
    bw[h][2] = xb + (size_t)f * CIN + cs * 8;
  }
  unsigned short* aDst[2];
  unsigned short* bDst[2];
#pragma unroll
  for (int h = 0; h < 2; ++h) {
    aDst[h] = As + h * 2048 + wid * 512;
    bDst[h] = Bs + h * 2048 + wid * 512;
  }
  int aoff[4], boff[4];
#pragma unroll
  for (int mi = 0; mi < 4; ++mi) {
    int r = wr * 64 + mi * 16 + l15;
    aoff[mi] = r * 32 + (kg ^ ((r >> 1) & 3)) * 8;
  }
#pragma unroll
  for (int ni = 0; ni < 4; ++ni) {
    int r = wc * 64 + ni * 16 + l15;
    boff[ni] = r * 32 + (kg ^ ((r >> 1) & 3)) * 8;
  }
  f32x4 acc[4][4] = {};
#pragma unroll
  for (int s = 0; s < 3; ++s) {
    for (int kt = 0; kt < 16; ++kt) {
      int koff = kt * 32;
#pragma unroll
      for (int h = 0; h < 2; ++h) {
        GLD16(aw[h] + s * CIN + koff, aDst[h]);
        GLD16(bw[h][s] + koff, bDst[h]);
      }
      __syncthreads();
      bf16x8 af[4], bf[4];
#pragma unroll
      for (int mi = 0; mi < 4; ++mi) af[mi] = *(const bf16x8*)(&As[aoff[mi]]);
#pragma unroll
      for (int ni = 0; ni < 4; ++ni) bf[ni] = *(const bf16x8*)(&Bs[boff[ni]]);
#pragma unroll
      for (int mi = 0; mi < 4; ++mi)
#pragma unroll
        for (int ni = 0; ni < 4; ++ni)
          acc[mi][ni] = MFMA(af[mi], bf[ni], acc[mi][ni]);
      __syncthreads();
    }
  }
  float* ob = out + (size_t)b * COUT * TT;
#pragma unroll
  for (int mi = 0; mi < 4; ++mi) {
    int m0 = row0 + wr * 64 + mi * 16 + kg * 4;
#pragma unroll
    for (int ni = 0; ni < 4; ++ni) {
      int t = t0 + wc * 64 + ni * 16 + l15;
#pragma unroll
      for (int j = 0; j < 4; ++j) {
        ob[(size_t)(m0 + j) * TT + t] = acc[mi][ni][j] + bias[m0 + j];
      }
    }
  }
}

extern "C" void kernel_launch(void* const* d_in, const int* in_sizes, int n_in,
                              void* d_out, int out_size, void* d_ws, size_t ws_size,
                              hipStream_t stream) {
  const float* x  = (const float*)d_in[0];
  const float* d  = (const float*)d_in[1];
  const float* W0 = (const float*)d_in[2];
  const float* b0 = (const float*)d_in[3];
  const float* W1 = (const float*)d_in[4];
  const float* W2 = (const float*)d_in[5];
  float* out = (float*)d_out;

  char* ws = (char*)d_ws;
  unsigned short* Wb  = (unsigned short*)ws;                       // 1.5 MiB
  unsigned short* xbT = (unsigned short*)(ws + (2u << 20));        // 8 MiB per batch
  const size_t SZ_XBT1 = (size_t)TT * CIN * 2;
  const size_t NEED_FULL = (size_t)(2u << 20) + (size_t)NB * SZ_XBT1;  // ~66 MiB
  const size_t NEED_MIN  = (size_t)(2u << 20) + SZ_XBT1;               // ~10 MiB

  if (ws_size >= NEED_MIN) {
    k_convert_w<<<dim3(1024, 3), 256, 0, stream>>>(W0, W1, W2, Wb);
    if (ws_size >= NEED_FULL) {
      k_transpose<<<dim3(TT / 64, CIN / 64, NB), 256, 0, stream>>>(x, xbT, 0);
      k_gemm256<<<dim3(NB, (TT / 256) * (COUT / 256), 1), 512, 0, stream>>>(
          Wb, xbT, d, b0, out);
    } else {
      for (int b = 0; b < NB; ++b) {
        k_transpose<<<dim3(TT / 64, CIN / 64, 1), 256, 0, stream>>>(x, xbT, b);
        k_gemm<<<dim3(COUT / 128, TT / 128, 1), 256, 0, stream>>>(Wb, xbT, d, b0, out, b);
      }
    }
  } else {
    for (int b = 0; b < NB; ++b) {
      k_transpose<<<dim3(TT / 64, CIN / 64, 1), 256, 0, stream>>>(x, xbT, b);
      k_gemm<<<dim3(COUT / 128, TT / 128, 1), 256, 0, stream>>>(Wb, xbT, d, b0, out, b);
    }
  }
}

// Round 13
// 140.423 us; speedup vs baseline: 3.4298x; 1.0128x over previous
//
#include <hip/hip_runtime.h>

#define TT 8192
#define CIN 512
#define COUT 512
#define NB 8
#define KTOT 1536   // 3 * CIN

typedef __attribute__((ext_vector_type(4))) float f32x4;
typedef __attribute__((ext_vector_type(8))) short bf16x8;

#define GLD16(g, l) __builtin_amdgcn_global_load_lds(                      \
    (const __attribute__((address_space(1))) void*)(g),                    \
    (__attribute__((address_space(3))) void*)(l), 16, 0, 0)

#define CFENCE() asm volatile("" ::: "memory")
#define SBAR() do { CFENCE(); __builtin_amdgcn_s_barrier(); CFENCE(); } while (0)
#define VMC_(n) asm volatile("s_waitcnt vmcnt(" #n ")" ::: "memory")
#define VMC(n) VMC_(n)
#define LGKM0() asm volatile("s_waitcnt lgkmcnt(0)" ::: "memory")
#define MFMA(a_, b_, c_) __builtin_amdgcn_mfma_f32_16x16x32_bf16((a_), (b_), (c_), 0, 0, 0)

__device__ inline unsigned short f2bf(float f) {
  union { float f; unsigned int u; } v; v.f = f;
  unsigned int u = v.u;
  unsigned int r = (u + 0x7FFFu + ((u >> 16) & 1u)) >> 16;  // RNE
  return (unsigned short)r;
}

__global__ void k_convert_w(const float* __restrict__ W0, const float* __restrict__ W1,
                            const float* __restrict__ W2, unsigned short* __restrict__ Wb) {
  int i = blockIdx.x * 256 + threadIdx.x;
  if (i >= COUT * CIN) return;
  const float* Ws = blockIdx.y == 0 ? W0 : (blockIdx.y == 1 ? W1 : W2);
  int o = i >> 9, c = i & 511;
  Wb[(size_t)o * KTOT + blockIdx.y * CIN + c] = f2bf(Ws[i]);
}

// x (B, C, T) fp32 -> xbT (T, C) bf16 per batch. grid (T/64, C/64, nb), block 256
__global__ void k_transpose(const float* __restrict__ x, unsigned short* __restrict__ xbT,
                            int b_base) {
  int b = b_base + blockIdx.z;
  const float* xb = x + (size_t)b * CIN * TT;
  unsigned short* xo = xbT + (size_t)blockIdx.z * TT * CIN;
  __shared__ float tile[64][65];
  int t0 = blockIdx.x * 64, c0 = blockIdx.y * 64;
  int tid = threadIdx.x;
#pragma unroll
  for (int it = 0; it < 16; ++it) {
    int L = it * 256 + tid;
    int c = L >> 6, t = L & 63;
    tile[c][t] = xb[(size_t)(c0 + c) * TT + (t0 + t)];
  }
  __syncthreads();
#pragma unroll
  for (int it = 0; it < 16; ++it) {
    int L = it * 256 + tid;
    int t = L >> 6, c = L & 63;
    xo[(size_t)(t0 + t) * CIN + (c0 + c)] = f2bf(tile[c][t]);
  }
}

// ---- 256x256 fused gather-GEMM, margin-shared B (one staged B-slice per c-tile,
//      read by all 3 segments with shifted rows), half-publish A pipeline ----
// grid (8, 64), block 512 (8 waves, 2M x 4N). id%8 = batch -> XCD.
// K-loop: outer ct (c-tile, 8) x inner s (segment, 3); A-tile k-index = s*8+ct.
// B-slice rows [t0-8, t0+312) x 64 c: exact for all dil <= 8 (bench: dil==1).
__global__ __launch_bounds__(512, 2) void k_gemm256(
    const unsigned short* __restrict__ Wb, const unsigned short* __restrict__ xbT,
    const float* __restrict__ d, const float* __restrict__ bias,
    float* __restrict__ out) {
  __shared__ __align__(16) unsigned short As[2][256 * 64];   // 64 KiB
  __shared__ __align__(16) unsigned short Bx[2][320 * 64];   // 80 KiB
  const int b = blockIdx.x;                    // batch = id%8 -> XCD
  const int t0 = (blockIdx.y >> 1) * 256;      // t-tile
  const int row0 = (blockIdx.y & 1) * 256;     // M-tile
  const unsigned short* xb = xbT + (size_t)b * TT * CIN;
  const int tid = threadIdx.x;
  const int lane = tid & 63, wid = tid >> 6;
  const int wr = wid >> 2, wc = wid & 3;
  const int l15 = lane & 15, kg = lane >> 4;

  // ---- per-lane B fragment rows for 3 segments (gather folded in) + predicate
  int bRd0[3][4];
  unsigned bmask = 0;
  int flag = 0;
#pragma unroll
  for (int f = 0; f < 4; ++f) {
    int nh = f >> 1, ni = f & 1;
    int t = t0 + wc * 64 + nh * 32 + ni * 16 + l15;
    float dv = d[(size_t)b * TT + t];
    int dil = (int)dv; if (dil < 1) dil = 1;
    flag |= (dil > 8);
    int dl = (dil > 8) ? 1 : dil;
    int p = t - dl; if (p < 0) p = -p;
    int f0 = t + dl;
    int fi = (f0 >= TT) ? (TT - 1 - (f0 - TT)) : f0;
    int rows[3] = { p - t0 + 8, t - t0 + 8, fi - t0 + 8 };
#pragma unroll
    for (int s = 0; s < 3; ++s) {
      int r = rows[s];
      int sr = (r >> 1) & 7;
      int slot = (kg ^ (sr & 3)) + (sr & 4);
      bRd0[s][f] = r * 64 + slot * 8;
      bmask |= ((unsigned)((sr >> 2) & 1)) << (s * 4 + f);
    }
  }
  if (__syncthreads_or(flag)) return;   // d too large: k_fb covers this t-chunk

  // ---- staging sources
  const int srow = tid >> 3;
  const int cSrc8 = (((tid & 7) ^ ((tid >> 4) & 7))) * 8;  // swizzled 16B chunk
  int aOff[4];     // Wb ushort offsets (+ kA*64 at call)
#pragma unroll
  for (int j = 0; j < 4; ++j)
    aOff[j] = (row0 + j * 64 + srow) * KTOT + cSrc8;
  int bSrc[5];     // xbT ushort offsets (+ ct*64 at call), rows t0-8+rnd*64+srow
#pragma unroll
  for (int rnd = 0; rnd < 5; ++rnd) {
    int t = t0 - 8 + rnd * 64 + srow;
    if (t < 0) t = 0;
    if (t > TT - 1) t = TT - 1;
    bSrc[rnd] = t * CIN + cSrc8;
  }

  // ---- A fragment read offsets (swizzled), as r12
  const int s7 = l15 >> 1;
  const int chunk0 = (kg ^ (s7 & 3)) + (s7 & 4);
  const int dK = (l15 & 8) ? -32 : 32;
  int aRd[2][4];
#pragma unroll
  for (int mh = 0; mh < 2; ++mh)
#pragma unroll
    for (int mi = 0; mi < 4; ++mi)
      aRd[mh][mi] = (wr * 128 + mh * 64 + mi * 16 + l15) * 64 + chunk0 * 8;

#define STAGE_A_G0(kA_, buf_) do {                                            \
    GLD16(Wb + aOff[0] + (kA_) * 64, &As[buf_][0 * 4096 + wid * 512]);        \
    GLD16(Wb + aOff[2] + (kA_) * 64, &As[buf_][2 * 4096 + wid * 512]);        \
  } while (0)
#define STAGE_A_G1(kA_, buf_) do {                                            \
    GLD16(Wb + aOff[1] + (kA_) * 64, &As[buf_][1 * 4096 + wid * 512]);        \
    GLD16(Wb + aOff[3] + (kA_) * 64, &As[buf_][3 * 4096 + wid * 512]);        \
  } while (0)
#define STAGE_B_R(rnd_, ctn_) \
    GLD16(xb + bSrc[rnd_] + (ctn_) * 64, &Bx[(ctn_) & 1][(rnd_) * 4096 + wid * 512])

#define BKH1(S_, F_) (bRd0[S_][F_] + (((bmask >> ((S_) * 4 + (F_))) & 1) ? -32 : 32))

  bf16x8 af[4][2], bf0[2][2], bf1[2][2];
  f32x4 acc[8][4] = {};

  // prologue: B(ct=0) all 5 rounds -> Bx[0]; A(step0: s=0,ct=0 -> kA=0) -> As[0]
  STAGE_B_R(0, 0); STAGE_B_R(1, 0); STAGE_B_R(2, 0); STAGE_B_R(3, 0); STAGE_B_R(4, 0);
  STAGE_A_G0(0, 0); STAGE_A_G1(0, 0);
  VMC(0);
  SBAR();

#define MF_Q00() do { _Pragma("unroll") for (int mi = 0; mi < 4; ++mi)        \
    _Pragma("unroll") for (int ni = 0; ni < 2; ++ni) {                        \
      acc[mi][ni] = MFMA(af[mi][0], bf0[ni][0], acc[mi][ni]);                 \
      acc[mi][ni] = MFMA(af[mi][1], bf0[ni][1], acc[mi][ni]); } } while (0)
#define MF_Q01() do { _Pragma("unroll") for (int mi = 0; mi < 4; ++mi)        \
    _Pragma("unroll") for (int ni = 0; ni < 2; ++ni) {                        \
      acc[mi][2 + ni] = MFMA(af[mi][0], bf1[ni][0], acc[mi][2 + ni]);         \
      acc[mi][2 + ni] = MFMA(af[mi][1], bf1[ni][1], acc[mi][2 + ni]); } } while (0)
#define MF_Q10() do { _Pragma("unroll") for (int mi = 0; mi < 4; ++mi)        \
    _Pragma("unroll") for (int ni = 0; ni < 2; ++ni) {                        \
      acc[4 + mi][ni] = MFMA(af[mi][0], bf0[ni][0], acc[4 + mi][ni]);         \
      acc[4 + mi][ni] = MFMA(af[mi][1], bf0[ni][1], acc[4 + mi][ni]); } } while (0)
#define MF_Q11() do { _Pragma("unroll") for (int mi = 0; mi < 4; ++mi)        \
    _Pragma("unroll") for (int ni = 0; ni < 2; ++ni) {                        \
      acc[4 + mi][2 + ni] = MFMA(af[mi][0], bf1[ni][0], acc[4 + mi][2 + ni]); \
      acc[4 + mi][2 + ni] = MFMA(af[mi][1], bf1[ni][1], acc[4 + mi][2 + ni]); } } while (0)

  // STEP: PH0{af mh0 + bf(s); stage A-g0(next)+B rounds; MFMA Q00+Q01; lgkm0;
  //           vmcnt(CM); BAR}  PH2{af mh1; stage A-g1(next); MFMA Q10+Q11;
  //           lgkm0; vmcnt(CE); BAR}
#define STEP(S_, KAN_, HASA_, HASB_, BR0_, BR1_, NB_, CM_, CE_) do {          \
    const int curA = (ct & 1) ^ ((S_) & 1);                                   \
    const int curB = ct & 1;                                                  \
    _Pragma("unroll") for (int mi = 0; mi < 4; ++mi) {                        \
      af[mi][0] = *(const bf16x8*)&As[curA][aRd[0][mi]];                      \
      af[mi][1] = *(const bf16x8*)&As[curA][aRd[0][mi] + dK];                 \
    }                                                                         \
    _Pragma("unroll") for (int ni = 0; ni < 2; ++ni) {                        \
      bf0[ni][0] = *(const bf16x8*)&Bx[curB][bRd0[S_][ni]];                   \
      bf0[ni][1] = *(const bf16x8*)&Bx[curB][BKH1(S_, ni)];                   \
      bf1[ni][0] = *(const bf16x8*)&Bx[curB][bRd0[S_][2 + ni]];               \
      bf1[ni][1] = *(const bf16x8*)&Bx[curB][BKH1(S_, 2 + ni)];               \
    }                                                                         \
    if (HASA_) STAGE_A_G0(KAN_, curA ^ 1);                                    \
    if (HASB_) { STAGE_B_R(BR0_, ct + 1); if ((NB_) > 1) STAGE_B_R(BR1_, ct + 1); } \
    __builtin_amdgcn_s_setprio(1);                                            \
    MF_Q00(); MF_Q01();                                                       \
    __builtin_amdgcn_s_setprio(0);                                            \
    LGKM0(); VMC(CM_); SBAR();                                                \
    _Pragma("unroll") for (int mi = 0; mi < 4; ++mi) {                        \
      af[mi][0] = *(const bf16x8*)&As[curA][aRd[1][mi]];                      \
      af[mi][1] = *(const bf16x8*)&As[curA][aRd[1][mi] + dK];                 \
    }                                                                         \
    if (HASA_) STAGE_A_G1(KAN_, curA ^ 1);                                    \
    __builtin_amdgcn_s_setprio(1);                                            \
    MF_Q10(); MF_Q11();                                                       \
    __builtin_amdgcn_s_setprio(0);                                            \
    LGKM0(); VMC(CE_); SBAR();                                                \
  } while (0)

#pragma unroll 1
  for (int ct = 0; ct < 7; ++ct) {
    STEP(0, 8 + ct, 1, 1, 0, 1, 2, 4, 4);
    STEP(1, 16 + ct, 1, 1, 2, 3, 2, 4, 4);
    STEP(2, ct + 1, 1, 1, 4, 4, 1, 3, 2);
  }
  {
    const int ct = 7;
    STEP(0, 15, 1, 0, 0, 0, 0, 2, 2);
    STEP(1, 23, 1, 0, 0, 0, 0, 2, 2);
    STEP(2, 0, 0, 0, 0, 0, 0, 0, 0);
  }

  // epilogue: bias + fp32 store
  float* ob = out + (size_t)b * COUT * TT;
#pragma unroll
  for (int mh = 0; mh < 2; ++mh)
#pragma unroll
    for (int mi = 0; mi < 4; ++mi) {
      int m0 = row0 + wr * 128 + mh * 64 + mi * 16 + kg * 4;
#pragma unroll
      for (int nh = 0; nh < 2; ++nh)
#pragma unroll
        for (int ni = 0; ni < 2; ++ni) {
          int t = t0 + wc * 64 + nh * 32 + ni * 16 + l15;
          f32x4 v = acc[mh * 4 + mi][nh * 2 + ni];
#pragma unroll
          for (int j = 0; j < 4; ++j)
            ob[(size_t)(m0 + j) * TT + t] = v[j] + bias[m0 + j];
        }
    }
}

// ---- fallback for tiles with dil > 8 (never triggers for d in [0,1)) ----
// grid (TT/256, NB), block 256: thread owns one t, loops all o.
__global__ void k_fb(const float* __restrict__ x, const float* __restrict__ d,
                     const float* __restrict__ W0, const float* __restrict__ b0,
                     const float* __restrict__ W1, const float* __restrict__ W2,
                     float* __restrict__ out) {
  int t0 = blockIdx.x * 256, b = blockIdx.y;
  int t = t0 + threadIdx.x;
  float dv = d[(size_t)b * TT + t];
  int dil = (int)dv; if (dil < 1) dil = 1;
  if (!__syncthreads_or(dil > 8)) return;   // fast kernel handled this chunk
  int p = t - dil; if (p < 0) p = -p; p &= (TT - 1);
  int f0 = t + dil;
  int f = (f0 >= TT) ? (TT - 1 - (f0 & (TT - 1))) : f0;
  const float* xb = x + (size_t)b * CIN * TT;
  for (int o = 0; o < COUT; ++o) {
    float a = b0[o];
    for (int c = 0; c < CIN; ++c) {
      const float* xc = xb + (size_t)c * TT;
      a += W0[o * CIN + c] * xc[p] + W1[o * CIN + c] * xc[t] + W2[o * CIN + c] * xc[f];
    }
    out[((size_t)b * COUT + o) * TT + t] = a;
  }
}

// ---------------- fallback 128x128 (small ws) ----------------
__global__ __launch_bounds__(256) void k_gemm(
    const unsigned short* __restrict__ Wb, const unsigned short* __restrict__ xbT,
    const float* __restrict__ d, const float* __restrict__ bias,
    float* __restrict__ out, int b_base) {
  __shared__ __align__(16) unsigned short As[128 * 32];
  __shared__ __align__(16) unsigned short Bs[128 * 32];
  int b = b_base + blockIdx.z;
  const unsigned short* xb = xbT + (size_t)blockIdx.z * TT * CIN;
  int row0 = blockIdx.x * 128;
  int t0 = blockIdx.y * 128;
  int tid = threadIdx.x;
  int lane = tid & 63, wid = tid >> 6;
  int wr = wid >> 1, wc = wid & 1;
  int l15 = lane & 15, kg = lane >> 4;
  int rs = tid >> 2, cch = tid & 3;

  const unsigned short* aw[2];
  const unsigned short* bw[2][3];
#pragma unroll
  for (int h = 0; h < 2; ++h) {
    int r = rs + h * 64;
    int cs = cch ^ ((r >> 1) & 3);
    aw[h] = Wb + (size_t)(row0 + r) * KTOT + cs * 8;
    int t = t0 + r;
    float dv = d[(size_t)b * TT + t];
    int dil = (int)dv; if (dil < 1) dil = 1;
    int p = t - dil; if (p < 0) p = -p; p &= (TT - 1);
    int f0 = t + dil;
    int f = (f0 >= TT) ? (TT - 1 - (f0 & (TT - 1))) : f0;
    bw[h][0] = xb + (size_t)p * CIN + cs * 8;
    bw[h][1] = xb + (size_t)t * CIN + cs * 8;
    bw[h][2] = xb + (size_t)f * CIN + cs * 8;
  }
  unsigned short* aDst[2];
  unsigned short* bDst[2];
#pragma unroll
  for (int h = 0; h < 2; ++h) {
    aDst[h] = As + h * 2048 + wid * 512;
    bDst[h] = Bs + h * 2048 + wid * 512;
  }
  int aoff[4], boff[4];
#pragma unroll
  for (int mi = 0; mi < 4; ++mi) {
    int r = wr * 64 + mi * 16 + l15;
    aoff[mi] = r * 32 + (kg ^ ((r >> 1) & 3)) * 8;
  }
#pragma unroll
  for (int ni = 0; ni < 4; ++ni) {
    int r = wc * 64 + ni * 16 + l15;
    boff[ni] = r * 32 + (kg ^ ((r >> 1) & 3)) * 8;
  }
  f32x4 acc[4][4] = {};
#pragma unroll
  for (int s = 0; s < 3; ++s) {
    for (int kt = 0; kt < 16; ++kt) {
      int koff = kt * 32;
#pragma unroll
      for (int h = 0; h < 2; ++h) {
        GLD16(aw[h] + s * CIN + koff, aDst[h]);
        GLD16(bw[h][s] + koff, bDst[h]);
      }
      __syncthreads();
      bf16x8 af[4], bf[4];
#pragma unroll
      for (int mi = 0; mi < 4; ++mi) af[mi] = *(const bf16x8*)(&As[aoff[mi]]);
#pragma unroll
      for (int ni = 0; ni < 4; ++ni) bf[ni] = *(const bf16x8*)(&Bs[boff[ni]]);
#pragma unroll
      for (int mi = 0; mi < 4; ++mi)
#pragma unroll
        for (int ni = 0; ni < 4; ++ni)
          acc[mi][ni] = MFMA(af[mi], bf[ni], acc[mi][ni]);
      __syncthreads();
    }
  }
  float* ob = out + (size_t)b * COUT * TT;
#pragma unroll
  for (int mi = 0; mi < 4; ++mi) {
    int m0 = row0 + wr * 64 + mi * 16 + kg * 4;
#pragma unroll
    for (int ni = 0; ni < 4; ++ni) {
      int t = t0 + wc * 64 + ni * 16 + l15;
#pragma unroll
      for (int j = 0; j < 4; ++j) {
        ob[(size_t)(m0 + j) * TT + t] = acc[mi][ni][j] + bias[m0 + j];
      }
    }
  }
}

extern "C" void kernel_launch(void* const* d_in, const int* in_sizes, int n_in,
                              void* d_out, int out_size, void* d_ws, size_t ws_size,
                              hipStream_t stream) {
  const float* x  = (const float*)d_in[0];
  const float* d  = (const float*)d_in[1];
  const float* W0 = (const float*)d_in[2];
  const float* b0 = (const float*)d_in[3];
  const float* W1 = (const float*)d_in[4];
  const float* W2 = (const float*)d_in[5];
  float* out = (float*)d_out;

  char* ws = (char*)d_ws;
  unsigned short* Wb  = (unsigned short*)ws;                       // 1.5 MiB
  unsigned short* xbT = (unsigned short*)(ws + (2u << 20));        // 8 MiB per batch
  const size_t SZ_XBT1 = (size_t)TT * CIN * 2;
  const size_t NEED_FULL = (size_t)(2u << 20) + (size_t)NB * SZ_XBT1;  // ~66 MiB
  const size_t NEED_MIN  = (size_t)(2u << 20) + SZ_XBT1;               // ~10 MiB

  if (ws_size >= NEED_MIN) {
    k_convert_w<<<dim3(1024, 3), 256, 0, stream>>>(W0, W1, W2, Wb);
    if (ws_size >= NEED_FULL) {
      k_transpose<<<dim3(TT / 64, CIN / 64, NB), 256, 0, stream>>>(x, xbT, 0);
      k_gemm256<<<dim3(NB, (TT / 256) * (COUT / 256), 1), 512, 0, stream>>>(
          Wb, xbT, d, b0, out);
      k_fb<<<dim3(TT / 256, NB), 256, 0, stream>>>(x, d, W0, b0, W1, W2, out);
    } else {
      for (int b = 0; b < NB; ++b) {
        k_transpose<<<dim3(TT / 64, CIN / 64, 1), 256, 0, stream>>>(x, xbT, b);
        k_gemm<<<dim3(COUT / 128, TT / 128, 1), 256, 0, stream>>>(Wb, xbT, d, b0, out, b);
      }
    }
  } else {
    for (int b = 0; b < NB; ++b) {
      k_transpose<<<dim3(TT / 64, CIN / 64, 1), 256, 0, stream>>>(x, xbT, b);
      k_gemm<<<dim3(COUT / 128, TT / 128, 1), 256, 0, stream>>>(Wb, xbT, d, b0, out, b);
    }
  }
}